// Round 4
// baseline (15144.957 us; speedup 1.0000x reference)
//
#include <hip/hip_runtime.h>
#include <hip/hip_bf16.h>

// SplineConv (degree-1 B-spline, DIM=2, K=5, open), N=100000, E=1600000, 32->32.
// R4: kill the fp32 atomic scatter. R3 proved the limiter is device-scope
//     atomicAdd throughput (occupancy 37->76% with ZERO time change; WRITE_SIZE
//     1.65GB = 51.6M atomics x 32B write-through sectors; ~35 G atomics/s
//     saturated). Rewrite as counting-sort-by-target (CSR in d_ws) + node-
//     parallel gather kernel: 4 lanes/node accumulate in registers, one
//     coalesced non-atomic write per node, with /deg + x@root + bias fused.

#define NN   100000
#define EE   1600000
#define KTOT 25
#define PITCH   40                  // bf16 per (k,i) row: 20 dwords
#define KSTRIDE (32 * PITCH + 8)    // k-stride 644 dwords: spreads bank spans
#define RPITCH  36                  // fp32 pitch for root weight rows (16B aligned)

// ws layout (int32 units): counts | offsets | cursor | blksum | sorted
#define WS_COUNTS  0
#define WS_OFFSETS 100000
#define WS_CURSOR  200000
#define WS_BLKSUM  300000
#define WS_SORTED  300128
#define SCAN_NBLK  98               // ceil(100000/1024)

__device__ __forceinline__ float bflo(unsigned d) {
    unsigned u = d << 16;
    return __builtin_bit_cast(float, u);
}
__device__ __forceinline__ float bfhi(unsigned d) {
    unsigned u = d & 0xffff0000u;
    return __builtin_bit_cast(float, u);
}

__global__ void hist_kernel(const int* __restrict__ eidx, int* __restrict__ counts) {
    for (int e = blockIdx.x * blockDim.x + threadIdx.x; e < EE; e += gridDim.x * blockDim.x)
        atomicAdd(&counts[eidx[e]], 1);
}

__global__ __launch_bounds__(1024)
void scan1_kernel(const int* __restrict__ counts, int* __restrict__ offsets,
                  int* __restrict__ blksum) {
    __shared__ int buf[2][1024];
    int tid = threadIdx.x;
    int gid = blockIdx.x * 1024 + tid;
    int v = (gid < NN) ? counts[gid] : 0;
    buf[0][tid] = v;
    __syncthreads();
    int s = 0;
    for (int off = 1; off < 1024; off <<= 1) {
        int t = buf[s][tid];
        if (tid >= off) t += buf[s][tid - off];
        buf[1 - s][tid] = t;
        s ^= 1;
        __syncthreads();
    }
    if (gid < NN) offsets[gid] = buf[s][tid] - v;      // exclusive
    if (tid == 1023) blksum[blockIdx.x] = buf[s][tid]; // block total (inclusive last)
}

__global__ void scan2_kernel(int* __restrict__ blksum) {
    if (blockIdx.x == 0 && threadIdx.x == 0) {
        int acc = 0;
        for (int i = 0; i < SCAN_NBLK; ++i) { int v = blksum[i]; blksum[i] = acc; acc += v; }
    }
}

__global__ __launch_bounds__(1024)
void scan3_kernel(int* __restrict__ offsets, const int* __restrict__ blksum,
                  int* __restrict__ cursor) {
    int gid = blockIdx.x * 1024 + threadIdx.x;
    if (gid < NN) {
        int o = offsets[gid] + blksum[blockIdx.x];
        offsets[gid] = o;
        cursor[gid] = o;
    }
}

__global__ void scatter_kernel(const int* __restrict__ eidx, int* __restrict__ cursor,
                               int* __restrict__ sorted) {
    for (int e = blockIdx.x * blockDim.x + threadIdx.x; e < EE; e += gridDim.x * blockDim.x) {
        int pos = atomicAdd(&cursor[eidx[e]], 1);
        sorted[pos] = e;
    }
}

__global__ __launch_bounds__(1024)
void node_kernel(const float* __restrict__ x,
                 const int* __restrict__ eidx,
                 const float* __restrict__ pseudo,
                 const float* __restrict__ weight,
                 const float* __restrict__ rootw,
                 const float* __restrict__ bias,
                 const int* __restrict__ offsets,
                 const int* __restrict__ counts,
                 const int* __restrict__ sorted,
                 float* __restrict__ out)
{
    __shared__ __hip_bfloat16 wl[KTOT * KSTRIDE];  // 64400 B
    __shared__ float rw[32 * RPITCH];              // 4608 B
    __shared__ float bs[32];

    for (int idx = threadIdx.x; idx < KTOT * 1024; idx += 1024) {
        int k = idx >> 10;
        int r = idx & 1023;
        wl[k * KSTRIDE + (r >> 5) * PITCH + (r & 31)] = __float2bfloat16(weight[idx]);
    }
    if (threadIdx.x < 1024) {
        int i = threadIdx.x >> 5, o = threadIdx.x & 31;
        rw[i * RPITCH + o] = rootw[threadIdx.x];
    }
    if (threadIdx.x < 32) bs[threadIdx.x] = bias[threadIdx.x];
    __syncthreads();

    int t = blockIdx.x * 1024 + threadIdx.x;
    int node = t >> 2;
    int sub = t & 3;
    int og = sub * 8;
    if (node >= NN) return;

    int start = offsets[node];
    int dg = counts[node];

    float y[8] = {0, 0, 0, 0, 0, 0, 0, 0};
    float X[32];

    for (int j = 0; j < dg; ++j) {
        int e = sorted[start + j];
        int col = eidx[EE + e];

        const float2 ps = *(const float2*)(pseudo + 2 * e);
        float p0 = ps.x * 4.0f;
        float p1 = ps.y * 4.0f;
        float l0f = floorf(p0), l1f = floorf(p1);
        float f0 = p0 - l0f, f1 = p1 - l1f;
        int l0 = (int)l0f, l1 = (int)l1f;
        int i0a = min(max(l0, 0), 4),     i0b = min(max(l0 + 1, 0), 4);
        int i1a = min(max(l1, 0), 4),     i1b = min(max(l1 + 1, 0), 4);
        float b0 = (1.0f - f0) * (1.0f - f1); int k0 = i0a + 5 * i1a;
        float b1 = (1.0f - f0) * f1;          int k1 = i0a + 5 * i1b;
        float b2 = f0 * (1.0f - f1);          int k2 = i0b + 5 * i1a;
        float b3 = f0 * f1;                   int k3 = i0b + 5 * i1b;

        const float4* xp = (const float4*)(x + col * 32);
        #pragma unroll
        for (int q = 0; q < 8; ++q) {
            float4 v = xp[q];
            X[4 * q]     = v.x;
            X[4 * q + 1] = v.y;
            X[4 * q + 2] = v.z;
            X[4 * q + 3] = v.w;
        }

        const __hip_bfloat16* pa = &wl[k0 * KSTRIDE + og];
        const __hip_bfloat16* pb = &wl[k1 * KSTRIDE + og];
        const __hip_bfloat16* pc = &wl[k2 * KSTRIDE + og];
        const __hip_bfloat16* pd = &wl[k3 * KSTRIDE + og];

        #pragma unroll
        for (int i = 0; i < 32; ++i) {
            float xi = X[i];
            uint4 wA = *(const uint4*)(pa + i * PITCH);
            uint4 wB = *(const uint4*)(pb + i * PITCH);
            uint4 wC = *(const uint4*)(pc + i * PITCH);
            uint4 wD = *(const uint4*)(pd + i * PITCH);
            const unsigned* A = (const unsigned*)&wA;
            const unsigned* B = (const unsigned*)&wB;
            const unsigned* C = (const unsigned*)&wC;
            const unsigned* D = (const unsigned*)&wD;
            #pragma unroll
            for (int h = 0; h < 4; ++h) {
                float wsL = b0 * bflo(A[h]) + b1 * bflo(B[h])
                          + b2 * bflo(C[h]) + b3 * bflo(D[h]);
                float wsH = b0 * bfhi(A[h]) + b1 * bfhi(B[h])
                          + b2 * bfhi(C[h]) + b3 * bfhi(D[h]);
                y[2 * h]     = fmaf(xi, wsL, y[2 * h]);
                y[2 * h + 1] = fmaf(xi, wsH, y[2 * h + 1]);
            }
        }
    }

    float inv = 1.0f / fmaxf((float)dg, 1.0f);
    #pragma unroll
    for (int c = 0; c < 8; ++c) y[c] *= inv;

    // Fused root term + bias: y += x[node] @ rootw
    const float4* xn = (const float4*)(x + node * 32);
    #pragma unroll
    for (int q = 0; q < 8; ++q) {
        float4 v = xn[q];
        X[4 * q]     = v.x;
        X[4 * q + 1] = v.y;
        X[4 * q + 2] = v.z;
        X[4 * q + 3] = v.w;
    }
    #pragma unroll
    for (int i = 0; i < 32; ++i) {
        float xi = X[i];
        float4 r0 = *(const float4*)(rw + i * RPITCH + og);
        float4 r1 = *(const float4*)(rw + i * RPITCH + og + 4);
        y[0] = fmaf(xi, r0.x, y[0]);
        y[1] = fmaf(xi, r0.y, y[1]);
        y[2] = fmaf(xi, r0.z, y[2]);
        y[3] = fmaf(xi, r0.w, y[3]);
        y[4] = fmaf(xi, r1.x, y[4]);
        y[5] = fmaf(xi, r1.y, y[5]);
        y[6] = fmaf(xi, r1.z, y[6]);
        y[7] = fmaf(xi, r1.w, y[7]);
    }
    #pragma unroll
    for (int c = 0; c < 8; ++c) y[c] += bs[og + c];

    float4* op = (float4*)(out + node * 32 + og);
    op[0] = make_float4(y[0], y[1], y[2], y[3]);
    op[1] = make_float4(y[4], y[5], y[6], y[7]);
}

extern "C" void kernel_launch(void* const* d_in, const int* in_sizes, int n_in,
                              void* d_out, int out_size, void* d_ws, size_t ws_size,
                              hipStream_t stream) {
    const float* x      = (const float*)d_in[0];
    const int*   eidx   = (const int*)d_in[1];
    const float* pseudo = (const float*)d_in[2];
    const float* weight = (const float*)d_in[3];
    const float* rootw  = (const float*)d_in[4];
    const float* bias   = (const float*)d_in[5];
    float* out = (float*)d_out;

    int* ws      = (int*)d_ws;
    int* counts  = ws + WS_COUNTS;
    int* offsets = ws + WS_OFFSETS;
    int* cursor  = ws + WS_CURSOR;
    int* blksum  = ws + WS_BLKSUM;
    int* sorted  = ws + WS_SORTED;

    hipMemsetAsync(counts, 0, (size_t)NN * sizeof(int), stream);

    hist_kernel   <<<2048, 256, 0, stream>>>(eidx, counts);
    scan1_kernel  <<<SCAN_NBLK, 1024, 0, stream>>>(counts, offsets, blksum);
    scan2_kernel  <<<1, 64, 0, stream>>>(blksum);
    scan3_kernel  <<<SCAN_NBLK, 1024, 0, stream>>>(offsets, blksum, cursor);
    scatter_kernel<<<2048, 256, 0, stream>>>(eidx, cursor, sorted);

    node_kernel<<<(NN * 4 + 1023) / 1024, 1024, 0, stream>>>(
        x, eidx, pseudo, weight, rootw, bias, offsets, counts, sorted, out);
}

// Round 5
// 6497.762 us; speedup vs baseline: 2.3308x; 2.3308x over previous
//
#include <hip/hip_runtime.h>
#include <hip/hip_bf16.h>

// SplineConv (degree-1 B-spline, DIM=2, K=5, open), N=100000, E=1600000, 32->32.
// R5: R4's node-gather spilled X[32] to scratch across a dynamic-degree loop
//     (FETCH 14.5GB / WRITE 23.4GB of HBM scratch traffic, VALUBusy 3%, 10x
//     regression). Revert to the proven R2/R3 edge body (straight-line, fixed
//     trip counts, float4 loads sunk into consumers, VGPR~28-52, no spill) but
//     run it over SORTED edges: each 4-lane team owns 16 consecutive sorted
//     edges, accumulates y[8] in registers across same-row runs, and flushes
//     with atomicAdd only at row boundaries -> ~6.2M atomic dwords vs 51.6M
//     (R3 proved device-scope fp32 atomic throughput was the limiter).
//     CSR build (hist/scan/scatter, ~165us measured) reused from R4.

#define NN   100000
#define EE   1600000
#define KTOT 25
#define PITCH   40                  // bf16 per (k,i) row: 20 dwords
#define KSTRIDE (32 * PITCH + 8)    // k-stride 644 dwords: spreads bank spans
#define RPITCH  36                  // fp32 pitch for root weight rows
#define TEDGE   16
#define NTEAMS  (EE / TEDGE)        // 100000 teams

// ws layout (int32 units): counts | offsets | cursor | blksum | sorted
#define WS_COUNTS  0
#define WS_OFFSETS 100000
#define WS_CURSOR  200000
#define WS_BLKSUM  300000
#define WS_SORTED  300128
#define SCAN_NBLK  98               // ceil(100000/1024)

__device__ __forceinline__ float bflo(unsigned d) {
    unsigned u = d << 16;
    return __builtin_bit_cast(float, u);
}
__device__ __forceinline__ float bfhi(unsigned d) {
    unsigned u = d & 0xffff0000u;
    return __builtin_bit_cast(float, u);
}

__global__ void hist_kernel(const int* __restrict__ eidx, int* __restrict__ counts) {
    for (int e = blockIdx.x * blockDim.x + threadIdx.x; e < EE; e += gridDim.x * blockDim.x)
        atomicAdd(&counts[eidx[e]], 1);
}

__global__ __launch_bounds__(1024)
void scan1_kernel(const int* __restrict__ counts, int* __restrict__ offsets,
                  int* __restrict__ blksum) {
    __shared__ int buf[2][1024];
    int tid = threadIdx.x;
    int gid = blockIdx.x * 1024 + tid;
    int v = (gid < NN) ? counts[gid] : 0;
    buf[0][tid] = v;
    __syncthreads();
    int s = 0;
    for (int off = 1; off < 1024; off <<= 1) {
        int t = buf[s][tid];
        if (tid >= off) t += buf[s][tid - off];
        buf[1 - s][tid] = t;
        s ^= 1;
        __syncthreads();
    }
    if (gid < NN) offsets[gid] = buf[s][tid] - v;      // exclusive
    if (tid == 1023) blksum[blockIdx.x] = buf[s][tid]; // block total
}

__global__ void scan2_kernel(int* __restrict__ blksum) {
    if (blockIdx.x == 0 && threadIdx.x == 0) {
        int acc = 0;
        for (int i = 0; i < SCAN_NBLK; ++i) { int v = blksum[i]; blksum[i] = acc; acc += v; }
    }
}

__global__ __launch_bounds__(1024)
void scan3_kernel(int* __restrict__ offsets, const int* __restrict__ blksum,
                  int* __restrict__ cursor) {
    int gid = blockIdx.x * 1024 + threadIdx.x;
    if (gid < NN) {
        int o = offsets[gid] + blksum[blockIdx.x];
        offsets[gid] = o;
        cursor[gid] = o;
    }
}

__global__ void scatter_kernel(const int* __restrict__ eidx, int* __restrict__ cursor,
                               int* __restrict__ sorted) {
    for (int e = blockIdx.x * blockDim.x + threadIdx.x; e < EE; e += gridDim.x * blockDim.x) {
        int pos = atomicAdd(&cursor[eidx[e]], 1);
        sorted[pos] = e;
    }
}

__global__ __launch_bounds__(512, 4)
void run_kernel(const float* __restrict__ x,
                const int* __restrict__ eidx,
                const float* __restrict__ pseudo,
                const float* __restrict__ weight,
                const int* __restrict__ sorted,
                float* __restrict__ acc)     // d_out as accumulator, pre-zeroed
{
    __shared__ __hip_bfloat16 wl[KTOT * KSTRIDE];   // 64400 B

    for (int idx = threadIdx.x; idx < KTOT * 1024; idx += 512) {
        int k = idx >> 10;
        int r = idx & 1023;
        wl[k * KSTRIDE + (r >> 5) * PITCH + (r & 31)] = __float2bfloat16(weight[idx]);
    }
    __syncthreads();

    const int team = (blockIdx.x * 512 + threadIdx.x) >> 2;
    const int sub  = threadIdx.x & 3;
    const int og   = sub * 8;
    if (team >= NTEAMS) return;

    const int base = team * TEDGE;
    int row_cur = eidx[sorted[base]];
    float y[8] = {0, 0, 0, 0, 0, 0, 0, 0};

    for (int j = 0; j < TEDGE; ++j) {
        int e = sorted[base + j];
        int row = eidx[e];
        if (row != row_cur) {           // uniform across the 4-lane team
            float* dst = acc + row_cur * 32 + og;
            #pragma unroll
            for (int c = 0; c < 8; ++c) { atomicAdd(dst + c, y[c]); y[c] = 0.0f; }
            row_cur = row;
        }
        int col = eidx[EE + e];

        // degree-1 spline basis, scale = K-1 = 4 (open)
        const float2 ps = *(const float2*)(pseudo + 2 * e);
        float p0 = ps.x * 4.0f;
        float p1 = ps.y * 4.0f;
        float l0f = floorf(p0), l1f = floorf(p1);
        float f0 = p0 - l0f, f1 = p1 - l1f;
        int l0 = (int)l0f, l1 = (int)l1f;
        int i0a = min(max(l0, 0), 4),     i0b = min(max(l0 + 1, 0), 4);
        int i1a = min(max(l1, 0), 4),     i1b = min(max(l1 + 1, 0), 4);
        float b0 = (1.0f - f0) * (1.0f - f1); int k0 = i0a + 5 * i1a;
        float b1 = (1.0f - f0) * f1;          int k1 = i0a + 5 * i1b;
        float b2 = f0 * (1.0f - f1);          int k2 = i0b + 5 * i1a;
        float b3 = f0 * f1;                   int k3 = i0b + 5 * i1b;

        const float4* xp = (const float4*)(x + col * 32);
        const __hip_bfloat16* pa = &wl[k0 * KSTRIDE + og];
        const __hip_bfloat16* pb = &wl[k1 * KSTRIDE + og];
        const __hip_bfloat16* pc = &wl[k2 * KSTRIDE + og];
        const __hip_bfloat16* pd = &wl[k3 * KSTRIDE + og];

        // i in groups of 4: one float4 of x live at a time (no X[32] array!)
        #pragma unroll
        for (int q = 0; q < 8; ++q) {
            float4 v = xp[q];
            float xq[4] = {v.x, v.y, v.z, v.w};
            #pragma unroll
            for (int r = 0; r < 4; ++r) {
                int i = 4 * q + r;
                float xi = xq[r];
                uint4 wA = *(const uint4*)(pa + i * PITCH);
                uint4 wB = *(const uint4*)(pb + i * PITCH);
                uint4 wC = *(const uint4*)(pc + i * PITCH);
                uint4 wD = *(const uint4*)(pd + i * PITCH);
                const unsigned* A = (const unsigned*)&wA;
                const unsigned* B = (const unsigned*)&wB;
                const unsigned* C = (const unsigned*)&wC;
                const unsigned* D = (const unsigned*)&wD;
                #pragma unroll
                for (int h = 0; h < 4; ++h) {
                    float wsL = b0 * bflo(A[h]) + b1 * bflo(B[h])
                              + b2 * bflo(C[h]) + b3 * bflo(D[h]);
                    float wsH = b0 * bfhi(A[h]) + b1 * bfhi(B[h])
                              + b2 * bfhi(C[h]) + b3 * bfhi(D[h]);
                    y[2 * h]     = fmaf(xi, wsL, y[2 * h]);
                    y[2 * h + 1] = fmaf(xi, wsH, y[2 * h + 1]);
                }
            }
        }
    }

    float* dst = acc + row_cur * 32 + og;
    #pragma unroll
    for (int c = 0; c < 8; ++c) atomicAdd(dst + c, y[c]);
}

__global__ __launch_bounds__(256)
void finalize_kernel(const float* __restrict__ x,
                     const float* __restrict__ rootw,  // [32*32] i-major
                     const float* __restrict__ bias,   // [32]
                     const int* __restrict__ counts,   // [N] degrees
                     float* __restrict__ out)          // [N*32] in/out
{
    __shared__ float rw[32 * RPITCH];
    __shared__ float bs[32];
    for (int idx = threadIdx.x; idx < 1024; idx += 256)
        rw[(idx >> 5) * RPITCH + (idx & 31)] = rootw[idx];
    if (threadIdx.x < 32) bs[threadIdx.x] = bias[threadIdx.x];
    __syncthreads();

    int tid = blockIdx.x * 256 + threadIdx.x;
    int n = tid >> 5, o = tid & 31;
    if (n >= NN) return;

    float xv = x[n * 32 + o];
    int gb = (threadIdx.x & 63) & ~31;
    float v = 0.0f;
    #pragma unroll
    for (int i = 0; i < 32; ++i) {
        float xi = __shfl(xv, gb + i, 64);
        v = fmaf(xi, rw[i * RPITCH + o], v);
    }
    float d = fmaxf((float)counts[n], 1.0f);
    int idx = n * 32 + o;
    out[idx] = out[idx] / d + v + bs[o];
}

extern "C" void kernel_launch(void* const* d_in, const int* in_sizes, int n_in,
                              void* d_out, int out_size, void* d_ws, size_t ws_size,
                              hipStream_t stream) {
    const float* x      = (const float*)d_in[0];
    const int*   eidx   = (const int*)d_in[1];
    const float* pseudo = (const float*)d_in[2];
    const float* weight = (const float*)d_in[3];
    const float* rootw  = (const float*)d_in[4];
    const float* bias   = (const float*)d_in[5];
    float* out = (float*)d_out;

    int* ws      = (int*)d_ws;
    int* counts  = ws + WS_COUNTS;
    int* offsets = ws + WS_OFFSETS;
    int* cursor  = ws + WS_CURSOR;
    int* blksum  = ws + WS_BLKSUM;
    int* sorted  = ws + WS_SORTED;

    hipMemsetAsync(counts, 0, (size_t)NN * sizeof(int), stream);
    hipMemsetAsync(out, 0, (size_t)NN * 32 * sizeof(float), stream);

    hist_kernel   <<<2048, 256, 0, stream>>>(eidx, counts);
    scan1_kernel  <<<SCAN_NBLK, 1024, 0, stream>>>(counts, offsets, blksum);
    scan2_kernel  <<<1, 64, 0, stream>>>(blksum);
    scan3_kernel  <<<SCAN_NBLK, 1024, 0, stream>>>(offsets, blksum, cursor);
    scatter_kernel<<<2048, 256, 0, stream>>>(eidx, cursor, sorted);

    run_kernel<<<(NTEAMS * 4 + 511) / 512, 512, 0, stream>>>(
        x, eidx, pseudo, weight, sorted, out);

    finalize_kernel<<<(NN * 32 + 255) / 256, 256, 0, stream>>>(
        x, rootw, bias, counts, out);
}